// Round 17
// baseline (79.170 us; speedup 1.0000x reference)
//
#include <hip/hip_runtime.h>

#define NCODES 512
#define DIM 128
#define NROWS (64*2048)          // 131072
#define QN (NROWS*DIM)           // 16777216
#define BLK_ROWS 256
#define NBLOCKS (NROWS/BLK_ROWS) // 512
#define NWAVES 8                 // 512 threads, 32 rows/wave

// ---------------- prep: per-code weight/bound tables ----------------
// w_k, ss_k=||e_k||^2, beta_k=w_k*ss_k, gamma_k=2|w_k|*||e_k||*(1+1e-5).
// Lower bound (any sign of w): L_k(S,|x|) = w_k*S + beta_k - gamma_k*|x|
// <= w_k*(S+ss_k-2 x.e_k) = d_k  (Cauchy-Schwarz; 1e-5 inflation covers
// float rounding of the bound itself).
__global__ void vq_prep(const float* __restrict__ emb, const float* __restrict__ scaling,
                        float* __restrict__ wv, float* __restrict__ ssv,
                        float* __restrict__ betav, float* __restrict__ gammav) {
  int k = blockIdx.x;
  int l = threadIdx.x; // 64 lanes
  float2 v = ((const float2*)(emb + k * DIM))[l];
  float ss = v.x * v.x + v.y * v.y;
#pragma unroll
  for (int m = 1; m < 64; m <<= 1) ss += __shfl_xor(ss, m);
  if (l == 0) {
    float hr = 40.0f + (float)k * (140.0f / 511.0f);
    float wt = 1.0f + scaling[k] * ((hr - 100.0f) * (1.0f / 70.0f));
    wv[k] = wt;
    ssv[k] = ss;
    betav[k] = wt * ss;
    gammav[k] = 2.0f * fabsf(wt) * sqrtf(ss) * (1.0f + 1e-5f);
  }
}

// ---------------- main: bound-pruned exact argmin ----------------
// 512 blocks x 512 threads (8 waves x 32 rows; lanes (g,lr): row rg*16+lr,
// dims c*32+g*8..+7). Per row: (1) kb = argmin_k L_k (bound scan: 512 codes
// x 2 fma, codes split 4-way by g, 2-step butterfly); (2) exact f32 dot at
// kb -> D, dW; (3) inclusive survivor check {k: L_k <= dW} -> if ANY (never
// on this data; handles exact ties/smallest-index), wave-uniform brute-force
// exact recompute of all its rows. No MFMA, no codebook staging, 8KB LDS.
struct SmemT {
  float w[NCODES];
  float ss[NCODES];
  float beta[NCODES];
  float gamma[NCODES];
  float lossp[NWAVES];
};

__global__ __launch_bounds__(512, 4) void vq_main(
    const float* __restrict__ x,
    const float* __restrict__ emb32,
    const float* __restrict__ wv,
    const float* __restrict__ ssv,
    const float* __restrict__ betav,
    const float* __restrict__ gammav,
    float* __restrict__ out_q,
    float* __restrict__ out_idx,
    float* __restrict__ out_loss) {
  __shared__ SmemT sm;
  const int tid = threadIdx.x;
  const int wave = tid >> 6, lane = tid & 63;
  const int g = lane >> 4, lr = lane & 15;
  const long rowbase = (long)blockIdx.x * BLK_ROWS + wave * 32;

  // --- Tables to LDS (one element per thread, 512 == NCODES).
  sm.w[tid] = wv[tid];
  sm.ss[tid] = ssv[tid];
  sm.beta[tid] = betav[tid];
  sm.gamma[tid] = gammav[tid];

  // --- Load x rows (f32 kept live for exact dots) + per-row S, |x|.
  float4 xv[2][4][2];
#pragma unroll
  for (int rg = 0; rg < 2; rg++) {
    const float* xr = x + (rowbase + rg * 16 + lr) * DIM + g * 8;
#pragma unroll
    for (int c = 0; c < 4; c++) {
      xv[rg][c][0] = *(const float4*)(xr + c * 32);
      xv[rg][c][1] = *(const float4*)(xr + c * 32 + 4);
    }
  }
  float srow[2], xn[2];
#pragma unroll
  for (int rg = 0; rg < 2; rg++) {
    float ss = 0.f;
#pragma unroll
    for (int c = 0; c < 4; c++) {
      float4 v0 = xv[rg][c][0];
      float4 v1 = xv[rg][c][1];
      ss += v0.x * v0.x + v0.y * v0.y + v0.z * v0.z + v0.w * v0.w;
      ss += v1.x * v1.x + v1.y * v1.y + v1.z * v1.z + v1.w * v1.w;
    }
    ss += __shfl_xor(ss, 16);
    ss += __shfl_xor(ss, 32);   // full row sum, replicated over the 4 g-lanes
    srow[rg] = ss;
    xn[rg] = sqrtf(ss);
  }
  __syncthreads();  // tables ready; LDS read-only until loss phase

  // --- (1) Bound scan: lane (g,lr) evaluates codes g*128..g*128+127 for its
  // row rg*16+lr; butterfly min over the 4 g-lanes (tie -> smaller k).
  int kb[2];
#pragma unroll
  for (int rg = 0; rg < 2; rg++) {
    float fmin = 3.4e38f;
    int imin = 0;
#pragma unroll 8
    for (int j = 0; j < 128; j++) {
      int k = g * 128 + j;
      float L = fmaf(-sm.gamma[k], xn[rg], fmaf(sm.w[k], srow[rg], sm.beta[k]));
      if (L < fmin) { fmin = L; imin = k; }
    }
#pragma unroll
    for (int m = 16; m <= 32; m <<= 1) {
      float of = __shfl_xor(fmin, m);
      int oi = __shfl_xor(imin, m);
      if (of < fmin || (of == fmin && oi < imin)) { fmin = of; imin = oi; }
    }
    kb[rg] = imin;
  }

  // --- (2) Exact f32 dot at kb -> D (unweighted), dW (weighted).
  int win[2];
  float Drow[2], dWv[2];
#pragma unroll
  for (int rg = 0; rg < 2; rg++) {
    const int k = kb[rg];
    const float* er = emb32 + k * DIM + g * 8;
    float p = 0.f;
#pragma unroll
    for (int c = 0; c < 4; c++) {
      float4 e0 = *(const float4*)(er + c * 32);
      float4 e1 = *(const float4*)(er + c * 32 + 4);
      float4 a0 = xv[rg][c][0], a1 = xv[rg][c][1];
      p = fmaf(a0.x, e0.x, p); p = fmaf(a0.y, e0.y, p);
      p = fmaf(a0.z, e0.z, p); p = fmaf(a0.w, e0.w, p);
      p = fmaf(a1.x, e1.x, p); p = fmaf(a1.y, e1.y, p);
      p = fmaf(a1.z, e1.z, p); p = fmaf(a1.w, e1.w, p);
    }
    p += __shfl_xor(p, 16);
    p += __shfl_xor(p, 32);
    float D = srow[rg] + sm.ss[k] - 2.0f * p;
    win[rg] = k;
    Drow[rg] = D;
    dWv[rg] = sm.w[k] * D;
  }

  // --- (3) Inclusive survivor check: any k!=kb with L_k <= dW (+eps)?
  int extra = 0;
#pragma unroll
  for (int rg = 0; rg < 2; rg++) {
    float thr = dWv[rg] + fabsf(dWv[rg]) * 1e-6f;
#pragma unroll 8
    for (int j = 0; j < 128; j++) {
      int k = g * 128 + j;
      float L = fmaf(-sm.gamma[k], xn[rg], fmaf(sm.w[k], srow[rg], sm.beta[k]));
      extra |= (L <= thr) & (k != kb[rg]);
    }
  }
  if (__any(extra)) {
    // Exact brute force over all codes for this wave's rows (wave-uniform,
    // provably correct incl. tie->smallest-index; never triggers on data
    // where the bound margin exceeds the Cauchy-Schwarz slack).
#pragma unroll
    for (int rg = 0; rg < 2; rg++) {
      float bd = 3.4e38f, bD = 0.f;
      int bi = 0;
      for (int k = 0; k < NCODES; k++) {
        const float* er = emb32 + k * DIM + g * 8;
        float p = 0.f;
#pragma unroll
        for (int c = 0; c < 4; c++) {
          float4 e0 = *(const float4*)(er + c * 32);
          float4 e1 = *(const float4*)(er + c * 32 + 4);
          float4 a0 = xv[rg][c][0], a1 = xv[rg][c][1];
          p = fmaf(a0.x, e0.x, p); p = fmaf(a0.y, e0.y, p);
          p = fmaf(a0.z, e0.z, p); p = fmaf(a0.w, e0.w, p);
          p = fmaf(a1.x, e1.x, p); p = fmaf(a1.y, e1.y, p);
          p = fmaf(a1.z, e1.z, p); p = fmaf(a1.w, e1.w, p);
        }
        p += __shfl_xor(p, 16);
        p += __shfl_xor(p, 32);
        float D = srow[rg] + sm.ss[k] - 2.0f * p;
        float dw = sm.w[k] * D;
        if (dw < bd) { bd = dw; bi = k; bD = D; }  // strict < : smallest idx
      }
      win[rg] = bi;
      Drow[rg] = bD;
    }
  }

  // --- Indices out + per-wave loss partial.
  if (g == 0) {
    out_idx[rowbase + lr] = (float)win[0];
    out_idx[rowbase + 16 + lr] = (float)win[1];
  }
  {
    float l0 = Drow[0] + Drow[1];      // replicated over the 4 g-lanes
    l0 += __shfl_xor(l0, 1);
    l0 += __shfl_xor(l0, 2);
    l0 += __shfl_xor(l0, 4);
    l0 += __shfl_xor(l0, 8);           // sum over the 16 lr-lanes = 32 rows
    if (lane == 0) sm.lossp[wave] = l0;
  }

  // --- Wave-owned store: gather f32 codebook rows (codes via compile-time
  // shfl from lane m which owns row rg*16+m), T14 batched 8+8.
  {
    const uint4* __restrict__ esrc = (const uint4*)emb32;   // 32 uint4/row
    uint4* __restrict__ outu = (uint4*)out_q + rowbase * 32;
    const int col = lane & 31;
    const int hi2 = lane >> 5;
    int scode[16];
#pragma unroll
    for (int it = 0; it < 16; it++) {
      const int row0 = 2 * it;          // compile-time
      const int rg = row0 >> 4;
      const int m = row0 & 15;          // even
      int c0 = __shfl(win[rg], m);
      int c1 = __shfl(win[rg], m + 1);
      scode[it] = hi2 ? c1 : c0;
    }
    uint4 vbuf[8];
#pragma unroll
    for (int j = 0; j < 8; j++)
      vbuf[j] = esrc[scode[j] * 32 + col];
#pragma unroll
    for (int j = 0; j < 8; j++)
      outu[j * 64 + lane] = vbuf[j];
#pragma unroll
    for (int j = 0; j < 8; j++)
      vbuf[j] = esrc[scode[8 + j] * 32 + col];
#pragma unroll
    for (int j = 0; j < 8; j++)
      outu[(8 + j) * 64 + lane] = vbuf[j];
  }

  // --- Per-block loss reduce + one atomic (512 atomics total).
  __syncthreads();
  if (wave == 0 && lane < NWAVES) {
    float s = sm.lossp[lane];
#pragma unroll
    for (int m = 1; m < NWAVES; m <<= 1) s += __shfl_xor(s, m);
    if (lane == 0) atomicAdd(out_loss, s * (1.6f / (float)QN));
  }
}

extern "C" void kernel_launch(void* const* d_in, const int* in_sizes, int n_in,
                              void* d_out, int out_size, void* d_ws, size_t ws_size,
                              hipStream_t stream) {
  const float* x = (const float*)d_in[0];
  const float* emb = (const float*)d_in[1];
  const float* scaling = (const float*)d_in[2];

  float* out_q = (float*)d_out;
  float* out_loss = out_q + QN;
  float* out_idx = out_q + QN + 1;

  float* wv = (float*)d_ws;            // 2KB
  float* ssv = wv + NCODES;            // 2KB
  float* betav = ssv + NCODES;         // 2KB
  float* gammav = betav + NCODES;      // 2KB

  hipMemsetAsync(out_loss, 0, sizeof(float), stream);
  vq_prep<<<NCODES, 64, 0, stream>>>(emb, scaling, wv, ssv, betav, gammav);
  vq_main<<<NBLOCKS, 512, 0, stream>>>(x, emb, wv, ssv, betav, gammav,
                                       out_q, out_idx, out_loss);
}

// Round 18
// 71.788 us; speedup vs baseline: 1.1028x; 1.1028x over previous
//
#include <hip/hip_runtime.h>

#define NCODES 512
#define DIM 128
#define NROWS (64*2048)          // 131072
#define QN (NROWS*DIM)           // 16777216
#define BLK_ROWS 256             // 4 waves x 64 rows
#define NBLOCKS (NROWS/BLK_ROWS) // 512
#define NWAVES 4

__device__ __forceinline__ unsigned umin_(unsigned a, unsigned b) { return a < b ? a : b; }
__device__ __forceinline__ unsigned umax_(unsigned a, unsigned b) { return a > b ? a : b; }

// ---------------- prep: per-code bound tables ----------------
// L_k(S,|x|) = w_k*S + beta_k - gamma_k*|x| <= d_k = w_k*(S+ss_k-2 x.e_k)
// (Cauchy-Schwarz; gamma inflated 1e-4 to dominate f32 rounding of L).
__global__ void vq_prep(const float* __restrict__ emb, const float* __restrict__ scaling,
                        float* __restrict__ wv, float* __restrict__ ssv,
                        float* __restrict__ betav, float* __restrict__ gammav) {
  int k = blockIdx.x;
  int l = threadIdx.x; // 64 lanes
  float2 v = ((const float2*)(emb + k * DIM))[l];
  float ss = v.x * v.x + v.y * v.y;
#pragma unroll
  for (int m = 1; m < 64; m <<= 1) ss += __shfl_xor(ss, m);
  if (l == 0) {
    float hr = 40.0f + (float)k * (140.0f / 511.0f);
    float wt = 1.0f + scaling[k] * ((hr - 100.0f) * (1.0f / 70.0f));
    wv[k] = wt;
    ssv[k] = ss;
    betav[k] = wt * ss;
    gammav[k] = 2.0f * fabsf(wt) * sqrtf(ss) * (1.0f + 1e-4f);
  }
}

// ---------------- main: lane-owns-row bound scan (SGPR tables) ----------------
// 512 blocks x 256 threads (4 waves x 64 rows; lane l owns row waverow+l).
// Scan: k-loop is wave-uniform -> wv/betav/gammav reads become s_loads; one
// fetch serves all 64 rows; min1/min2 packed-u32 per lane (7 VALU/code), no
// LDS, no MFMA. Exactness: m2L > dW proves kb is the unique argmin (all other
// L <= d); else per-lane brute-force fallback (ties -> smallest k). R17's
// failure modes (1536 conflicted ds_reads, 64-reg spill) are structurally
// removed: LDS=16B, VGPR ~60.
__global__ __launch_bounds__(256, 4) void vq_main(
    const float* __restrict__ x,
    const float* __restrict__ emb32,
    const float* __restrict__ wv,
    const float* __restrict__ ssv,
    const float* __restrict__ betav,
    const float* __restrict__ gammav,
    float* __restrict__ out_q,
    float* __restrict__ out_idx,
    float* __restrict__ out_loss) {
  __shared__ float lossp[NWAVES];
  const int tid = threadIdx.x;
  const int wave = tid >> 6, lane = tid & 63;
  const int q8 = lane >> 3, c8 = lane & 7;   // worker coords: row-sub, dim-chunk
  const long rowW = (long)blockIdx.x * BLK_ROWS + wave * 64;

  // ---- Phase L: per-row S (cooperative: 8 lanes/row, 64B contiguous each).
  float S = 0.f;
#pragma unroll
  for (int it = 0; it < 8; ++it) {
    const float4* xr = (const float4*)(x + (rowW + it * 8 + q8) * DIM + c8 * 16);
    float4 a = xr[0], b = xr[1], c = xr[2], d = xr[3];
    float ssp = a.x*a.x + a.y*a.y + a.z*a.z + a.w*a.w
              + b.x*b.x + b.y*b.y + b.z*b.z + b.w*b.w
              + c.x*c.x + c.y*c.y + c.z*c.z + c.w*c.w
              + d.x*d.x + d.y*d.y + d.z*d.z + d.w*d.w;
    ssp += __shfl_xor(ssp, 1);
    ssp += __shfl_xor(ssp, 2);
    ssp += __shfl_xor(ssp, 4);                 // full-row S at its 8 workers
    float got = __shfl(ssp, (lane & 7) << 3);  // owner pulls its row's S
    if (q8 == it) S = got;                     // it compile-time -> cndmask
  }
  const float xn = sqrtf(S);

  // ---- Phase SCAN: packed min1/min2 over all 512 codes, tables via s_load.
  unsigned m1 = 0xFFFFFFFFu, m2 = 0xFFFFFFFFu;
#pragma unroll 16
  for (int k = 0; k < NCODES; ++k) {
    float w = wv[k], be = betav[k], ga = gammav[k];  // uniform -> SGPR
    float L = fmaf(-ga, xn, fmaf(w, S, be));         // >= 0 (w>0)
    unsigned u = (__builtin_bit_cast(unsigned, L) & 0xFFFFFE00u) | (unsigned)k;
    unsigned mx = umax_(m1, u);
    m2 = umin_(m2, mx);
    m1 = umin_(m1, u);
  }
  const int kb = (int)(m1 & 511u);
  const float ssb = ssv[kb], wb = wv[kb];    // per-lane scattered, L1-hot 2KB

  // ---- Phase DOT: exact f32 dot at kb (cooperative; x re-read is L2-hot).
  float D = 0.f, dW = 0.f;
#pragma unroll
  for (int it = 0; it < 8; ++it) {
    const int srcl = it * 8 + q8;
    const int kr = __shfl(kb, srcl);         // row (it*8+q8)'s candidate
    const float4* xr = (const float4*)(x + (rowW + it * 8 + q8) * DIM + c8 * 16);
    const float4* er = (const float4*)(emb32 + kr * DIM + c8 * 16);
    float4 xa = xr[0], xb = xr[1], xc = xr[2], xd = xr[3];
    float4 ea = er[0], eb = er[1], ec = er[2], ed = er[3];
    float p = 0.f;
    p = fmaf(xa.x, ea.x, p); p = fmaf(xa.y, ea.y, p);
    p = fmaf(xa.z, ea.z, p); p = fmaf(xa.w, ea.w, p);
    p = fmaf(xb.x, eb.x, p); p = fmaf(xb.y, eb.y, p);
    p = fmaf(xb.z, eb.z, p); p = fmaf(xb.w, eb.w, p);
    p = fmaf(xc.x, ec.x, p); p = fmaf(xc.y, ec.y, p);
    p = fmaf(xc.z, ec.z, p); p = fmaf(xc.w, ec.w, p);
    p = fmaf(xd.x, ed.x, p); p = fmaf(xd.y, ed.y, p);
    p = fmaf(xd.z, ed.z, p); p = fmaf(xd.w, ed.w, p);
    p += __shfl_xor(p, 1);
    p += __shfl_xor(p, 2);
    p += __shfl_xor(p, 4);
    float got = __shfl(p, (lane & 7) << 3);
    if (q8 == it) {
      D = fmaf(-2.0f, got, S + ssb);
      dW = wb * D;
    }
  }

  // ---- Phase VERIFY: if any other bound could beat dW, brute-force exactly.
  int win = kb;
  {
    float m2L = __builtin_bit_cast(float, m2 & 0xFFFFFE00u);
    float thr = fmaf(fabsf(dW), 1e-5f, dW + 1e-6f);
    if (m2L <= thr) {      // ~never on this data; exact + tie->smallest k
      float bd = 3.4e38f, bD = 0.f;
      int bi = 0;
      const float* xr = x + (rowW + lane) * DIM;
      for (int k = 0; k < NCODES; ++k) {
        const float* er = emb32 + k * DIM;
        float p = 0.f;
        for (int d = 0; d < DIM; ++d) p = fmaf(xr[d], er[d], p);
        float D2 = S + ssv[k] - 2.0f * p;
        float dw2 = wv[k] * D2;
        if (dw2 < bd) { bd = dw2; bi = k; bD = D2; }
      }
      win = bi;
      D = bD;
    }
  }

  // ---- Indices (coalesced) + per-wave loss partial.
  out_idx[rowW + lane] = (float)win;
  {
    float l0 = D;
#pragma unroll
    for (int m = 1; m < 64; m <<= 1) l0 += __shfl_xor(l0, m);
    if (lane == 0) lossp[wave] = l0;
  }

  // ---- STORE: gather f32 codebook rows (L2-hot), 2-row batches.
#pragma unroll
  for (int it = 0; it < 8; it += 2) {
    const int kA = __shfl(win, it * 8 + q8);
    const int kB = __shfl(win, (it + 1) * 8 + q8);
    const float4* eA = (const float4*)(emb32 + kA * DIM + c8 * 16);
    const float4* eB = (const float4*)(emb32 + kB * DIM + c8 * 16);
    float4 a0 = eA[0], a1 = eA[1], a2 = eA[2], a3 = eA[3];
    float4 b0 = eB[0], b1 = eB[1], b2 = eB[2], b3 = eB[3];
    float4* oA = (float4*)(out_q + (rowW + it * 8 + q8) * DIM + c8 * 16);
    float4* oB = (float4*)(out_q + (rowW + (it + 1) * 8 + q8) * DIM + c8 * 16);
    oA[0] = a0; oA[1] = a1; oA[2] = a2; oA[3] = a3;
    oB[0] = b0; oB[1] = b1; oB[2] = b2; oB[3] = b3;
  }

  // ---- Block loss reduce + one atomic (512 total).
  __syncthreads();
  if (wave == 0) {
    float s = (lane < NWAVES) ? lossp[lane] : 0.f;
    s += __shfl_xor(s, 1);
    s += __shfl_xor(s, 2);
    if (lane == 0) atomicAdd(out_loss, s * (1.6f / (float)QN));
  }
}

extern "C" void kernel_launch(void* const* d_in, const int* in_sizes, int n_in,
                              void* d_out, int out_size, void* d_ws, size_t ws_size,
                              hipStream_t stream) {
  const float* x = (const float*)d_in[0];
  const float* emb = (const float*)d_in[1];
  const float* scaling = (const float*)d_in[2];

  float* out_q = (float*)d_out;
  float* out_loss = out_q + QN;
  float* out_idx = out_q + QN + 1;

  float* wv = (float*)d_ws;            // 2KB
  float* ssv = wv + NCODES;            // 2KB
  float* betav = ssv + NCODES;         // 2KB
  float* gammav = betav + NCODES;      // 2KB

  hipMemsetAsync(out_loss, 0, sizeof(float), stream);
  vq_prep<<<NCODES, 64, 0, stream>>>(emb, scaling, wv, ssv, betav, gammav);
  vq_main<<<NBLOCKS, 256, 0, stream>>>(x, emb, wv, ssv, betav, gammav,
                                       out_q, out_idx, out_loss);
}